// Round 1
// baseline (260.190 us; speedup 1.0000x reference)
//
#include <hip/hip_runtime.h>
#include <hip/hip_bf16.h>

typedef float f32x4 __attribute__((ext_vector_type(4)));
typedef short bfx8 __attribute__((ext_vector_type(8)));   // 8 bf16 in 4 VGPRs

static __device__ __forceinline__ unsigned short f2bf(float f) {
    return __builtin_bit_cast(unsigned short, __float2bfloat16(f));
}

// ---------------------------------------------------------------------------
// Kernel 0: cast + transpose weights into WcatT[768][768] bf16.
// Row n (0..767): n<256 -> Wq col, 256..511 -> Wk, 512..767 -> Wv.
// WcatT[n][e] = W_which[e][n&255]
// ---------------------------------------------------------------------------
__global__ void prep_w(const float* __restrict__ Wk, const float* __restrict__ Wq,
                       const float* __restrict__ Wv, unsigned short* __restrict__ WT) {
    const int n = blockIdx.x;       // 0..767
    const int e = threadIdx.x;      // 0..767
    const int which = n >> 8;
    const int h = n & 255;
    const float* W = (which == 0) ? Wq : (which == 1) ? Wk : Wv;
    WT[(size_t)n * 768 + e] = f2bf(W[(size_t)e * 256 + h]);
}

// ---------------------------------------------------------------------------
// Kernel 1: QKV = X @ [Wq|Wk|Wv].  X: [65536,768] f32.  Out: bf16 in ws.
//   Q: qkv[(b*3+0)<<15 + t*256 + h]
//   K: qkv[(b*3+1)<<15 + s*256 + h]
//   V: qkv[(b*3+2)<<15 + h*128 + s]   (transposed for attention B-operand)
// 128x128 tile per block, 4 waves (2x2), BK=64, 16x16x32 bf16 MFMA.
// ---------------------------------------------------------------------------
#define LDT 72   // 64 + 8 pad: row stride 144B -> conflict-free ds_read_b128

__global__ __launch_bounds__(256) void qkv_gemm(const float* __restrict__ X,
                                                const unsigned short* __restrict__ WT,
                                                unsigned short* __restrict__ QKV) {
    __shared__ unsigned short Ab[128][LDT];
    __shared__ unsigned short Bb[128][LDT];

    const int tid = threadIdx.x;
    const int bn = blockIdx.x;           // 0..5   (fast: 6 n-blocks share X tile)
    const int bm = blockIdx.y;           // 0..511
    const int m0 = bm * 128;
    const int n0 = bn * 128;
    const int w = tid >> 6, lane = tid & 63;
    const int wr = w >> 1, wc = w & 1;
    const int lrow = lane & 15, lhi = lane >> 4;

    f32x4 acc[4][4];
    const f32x4 zero = {0.f, 0.f, 0.f, 0.f};
#pragma unroll
    for (int i = 0; i < 4; ++i)
#pragma unroll
        for (int j = 0; j < 4; ++j) acc[i][j] = zero;

    for (int kt = 0; kt < 12; ++kt) {
        const int k0 = kt * 64;
        // stage A: 128x64 f32 -> bf16 (reg-staged, padded)
#pragma unroll
        for (int i = 0; i < 8; ++i) {
            int f = i * 256 + tid;
            int row = f >> 4, c4 = (f & 15) * 4;
            float4 v = *(const float4*)(X + (size_t)(m0 + row) * 768 + k0 + c4);
            ushort4 u = make_ushort4(f2bf(v.x), f2bf(v.y), f2bf(v.z), f2bf(v.w));
            *(ushort4*)&Ab[row][c4] = u;
        }
        // stage B: WcatT rows n0..n0+127, cols k0..k0+63 (already bf16)
#pragma unroll
        for (int i = 0; i < 4; ++i) {
            int f = i * 256 + tid;
            int row = f >> 3, c8 = (f & 7) * 8;
            bfx8 vb = *(const bfx8*)(WT + (size_t)(n0 + row) * 768 + k0 + c8);
            *(bfx8*)&Bb[row][c8] = vb;
        }
        __syncthreads();
#pragma unroll
        for (int kk = 0; kk < 2; ++kk) {
            const int kb = kk * 32 + lhi * 8;
            bfx8 a[4], bb[4];
#pragma unroll
            for (int mi = 0; mi < 4; ++mi)
                a[mi] = *(const bfx8*)&Ab[wr * 64 + mi * 16 + lrow][kb];
#pragma unroll
            for (int ni = 0; ni < 4; ++ni)
                bb[ni] = *(const bfx8*)&Bb[wc * 64 + ni * 16 + lrow][kb];
#pragma unroll
            for (int mi = 0; mi < 4; ++mi)
#pragma unroll
                for (int ni = 0; ni < 4; ++ni)
                    acc[mi][ni] = __builtin_amdgcn_mfma_f32_16x16x32_bf16(
                        a[mi], bb[ni], acc[mi][ni], 0, 0, 0);
        }
        __syncthreads();
    }

    // epilogue: C/D layout row = 4*lhi + j, col = lrow (within 16x16 frag)
    const int b = bm;
#pragma unroll
    for (int mi = 0; mi < 4; ++mi) {
#pragma unroll
        for (int ni = 0; ni < 4; ++ni) {
            const int t = wr * 64 + mi * 16 + lhi * 4;
            const int N = n0 + wc * 64 + ni * 16 + lrow;
            const int which = N >> 8, h = N & 255;
            const size_t base = ((size_t)(b * 3 + which)) << 15;
#pragma unroll
            for (int j = 0; j < 4; ++j) {
                size_t idx = (which < 2) ? base + (size_t)(t + j) * 256 + h
                                         : base + (size_t)h * 128 + (t + j);
                QKV[idx] = f2bf(acc[mi][ni][j]);
            }
        }
    }
}

// ---------------------------------------------------------------------------
// Kernel 2: per-batch causal attention. 1 block = 1 batch, 512 thr (8 waves),
// each wave owns 16 q-rows. K in LDS [s][h] (padded), V in LDS [h][s]
// (pre-transposed by GEMM epilogue), P round-trips through retired K area.
// ---------------------------------------------------------------------------
__global__ __launch_bounds__(512) void attn(const unsigned short* __restrict__ QKV,
                                            float* __restrict__ Out) {
    __shared__ unsigned short Kl[128][264];   // 67584 B (row stride 528B)
    __shared__ unsigned short Vt[256][136];   // 69632 B (row stride 272B)

    const int b = blockIdx.x;
    const int tid = threadIdx.x;
    const int w = tid >> 6, lane = tid & 63;
    const int lrow = lane & 15, lhi = lane >> 4;

    const unsigned short* Qb = QKV + ((size_t)(b * 3 + 0) << 15);
    const unsigned short* Kb = QKV + ((size_t)(b * 3 + 1) << 15);
    const unsigned short* Vb = QKV + ((size_t)(b * 3 + 2) << 15);

    // Q fragments for this wave's 16 rows (A operand, rows = lrow)
    const int t0 = w * 16;
    bfx8 aq[8];
#pragma unroll
    for (int kk = 0; kk < 8; ++kk)
        aq[kk] = *(const bfx8*)(Qb + (size_t)(t0 + lrow) * 256 + kk * 32 + lhi * 8);

    // cooperative stage of K [128][256] and Vt [256][128]
#pragma unroll
    for (int i = 0; i < 8; ++i) {
        int f = i * 512 + tid;
        {
            int row = f >> 5, c = (f & 31) * 8;
            *(bfx8*)&Kl[row][c] = *(const bfx8*)(Kb + (size_t)row * 256 + c);
        }
        {
            int row = f >> 4, c = (f & 15) * 8;
            *(bfx8*)&Vt[row][c] = *(const bfx8*)(Vb + (size_t)row * 128 + c);
        }
    }
    __syncthreads();

    // scores S[16][128] per wave: S = Q K^T  (B operand = K rows, contiguous h)
    f32x4 sacc[8];
    const f32x4 zero = {0.f, 0.f, 0.f, 0.f};
#pragma unroll
    for (int sj = 0; sj < 8; ++sj) sacc[sj] = zero;
#pragma unroll
    for (int kk = 0; kk < 8; ++kk) {
        const int kb = kk * 32 + lhi * 8;
#pragma unroll
        for (int sj = 0; sj < 8; ++sj) {
            bfx8 bk = *(const bfx8*)&Kl[sj * 16 + lrow][kb];
            sacc[sj] = __builtin_amdgcn_mfma_f32_16x16x32_bf16(aq[kk], bk, sacc[sj], 0, 0, 0);
        }
    }

    // scale + causal mask + row softmax (rows live on 16-lane groups)
    const float scale = 0.03608439182435161f;   // 1/sqrt(768)
    float inv[4];
#pragma unroll
    for (int j = 0; j < 4; ++j) {
        const int t = t0 + lhi * 4 + j;
        float m = -1e30f;
#pragma unroll
        for (int sj = 0; sj < 8; ++sj) {
            int s = sj * 16 + lrow;
            float vv = sacc[sj][j] * scale;
            vv = (s <= t) ? vv : -1e30f;
            sacc[sj][j] = vv;
            m = fmaxf(m, vv);
        }
#pragma unroll
        for (int d = 1; d < 16; d <<= 1) m = fmaxf(m, __shfl_xor(m, d));
        float sum = 0.f;
#pragma unroll
        for (int sj = 0; sj < 8; ++sj) {
            float e = __expf(sacc[sj][j] - m);
            sacc[sj][j] = e;
            sum += e;
        }
#pragma unroll
        for (int d = 1; d < 16; d <<= 1) sum += __shfl_xor(sum, d);
        inv[j] = 1.0f / sum;
    }

    __syncthreads();   // all waves done reading Kl -> safe to reuse as P buffer

    // write P (bf16) into retired K area: per-wave [16][136] (row stride 272B)
    unsigned short* Pl = &Kl[0][0] + (size_t)w * (16 * 136);
#pragma unroll
    for (int sj = 0; sj < 8; ++sj)
#pragma unroll
        for (int j = 0; j < 4; ++j)
            Pl[(lhi * 4 + j) * 136 + sj * 16 + lrow] = f2bf(sacc[sj][j] * inv[j]);

    // O = P V : A = P rows (lrow), B = Vt rows = h columns of V
    bfx8 pa[4];
#pragma unroll
    for (int kk = 0; kk < 4; ++kk)
        pa[kk] = *(const bfx8*)(Pl + lrow * 136 + kk * 32 + lhi * 8);

    f32x4 oacc[16];
#pragma unroll
    for (int ni = 0; ni < 16; ++ni) oacc[ni] = zero;
#pragma unroll
    for (int ni = 0; ni < 16; ++ni) {
#pragma unroll
        for (int kk = 0; kk < 4; ++kk) {
            bfx8 bv = *(const bfx8*)&Vt[ni * 16 + lrow][kk * 32 + lhi * 8];
            oacc[ni] = __builtin_amdgcn_mfma_f32_16x16x32_bf16(pa[kk], bv, oacc[ni], 0, 0, 0);
        }
    }

    float* Ob = Out + (size_t)b * 128 * 256;
#pragma unroll
    for (int ni = 0; ni < 16; ++ni) {
#pragma unroll
        for (int j = 0; j < 4; ++j) {
            const int t = t0 + lhi * 4 + j;
            const int h = ni * 16 + lrow;
            Ob[(size_t)t * 256 + h] = oacc[ni][j];
        }
    }
}

// ---------------------------------------------------------------------------
extern "C" void kernel_launch(void* const* d_in, const int* in_sizes, int n_in,
                              void* d_out, int out_size, void* d_ws, size_t ws_size,
                              hipStream_t stream) {
    (void)in_sizes; (void)n_in; (void)out_size; (void)ws_size;
    const float* X  = (const float*)d_in[0];   // res_stream [512,128,768]
    const float* Wk = (const float*)d_in[1];   // [768,256]
    const float* Wq = (const float*)d_in[2];
    const float* Wv = (const float*)d_in[3];

    unsigned short* WT  = (unsigned short*)d_ws;          // 768*768 bf16 = 1.18MB
    unsigned short* QKV = WT + (size_t)768 * 768;         // 512*3*32768 bf16 = 50.3MB
    float* Out = (float*)d_out;

    prep_w<<<768, 768, 0, stream>>>(Wk, Wq, Wv, WT);
    qkv_gemm<<<dim3(6, 512), 256, 0, stream>>>(X, WT, QKV);
    attn<<<512, 512, 0, stream>>>(QKV, Out);
}